// Round 14
// baseline (312.589 us; speedup 1.0000x reference)
//
#include <hip/hip_runtime.h>
#include <hip/hip_bf16.h>
#include <cstddef>

// ---------------------------------------------------------------------------
// Problem dims
// ---------------------------------------------------------------------------
#define VOCAB 50000
#define EDIM  200
#define HDIM  128
#define BB 16
#define RR 10
#define SS 20
#define WW 64
#define NSENT (BB*RR*SS)   // 3200 word-level sequences
#define NREV  (BB*RR)      // 160 sentence-level sequences
#define G3    (3*HDIM)     // 384 gate rows per direction
#define NPROJ (2*G3)       // 768

// ---------------------------------------------------------------------------
// bf16 + fast-math helpers
// ---------------------------------------------------------------------------
static __device__ __forceinline__ short f2bf(float f) {    // RNE (for lo parts)
    union { float f; unsigned u; } v; v.f = f;
    unsigned r = v.u + 0x7FFFu + ((v.u >> 16) & 1u);
    return (short)(r >> 16);
}
static __device__ __forceinline__ short f2bf_t(float f) {  // truncate (hi parts)
    union { float f; unsigned u; } v; v.f = f;
    return (short)(v.u >> 16);
}
static __device__ __forceinline__ float bf2f(short s) {
    union { unsigned u; float f; } v;
    v.u = ((unsigned)(unsigned short)s) << 16;
    return v.f;
}
static __device__ __forceinline__ float frcp(float x) {
    return __builtin_amdgcn_rcpf(x);
}
static __device__ __forceinline__ float fsigmoid(float x) {
    return frcp(1.f + __expf(-x));
}
static __device__ __forceinline__ float ftanh(float x) {
    float y = __expf(-2.f * fabsf(x));
    float t = (1.f - y) * frcp(1.f + y);
    return copysignf(t, x);
}

using bf16x8 = __attribute__((ext_vector_type(8))) short;
using f32x4  = __attribute__((ext_vector_type(4))) float;

// ---------------------------------------------------------------------------
// preconv: f32 [.][KREAL] -> split-bf16 [.][KPAD] blobs (round-11 proven).
// ---------------------------------------------------------------------------
template<int KREAL, int KPAD>
__global__ __launch_bounds__(256) void preconv(
    const float* __restrict__ A0, int Mreal,
    short* __restrict__ hi, short* __restrict__ lo, int ngroups)
{
    int g = blockIdx.x * 256 + threadIdx.x;
    if (g >= ngroups) return;
    int row = g / (KPAD / 8);
    int k   = (g % (KPAD / 8)) * 8;
    float v[8];
    if (row < Mreal && k < KREAL) {   // KREAL % 8 == 0 -> no straddle
        const float* p = A0 + (size_t)row * KREAL + k;
        float4 a = *(const float4*)p;
        float4 b = *(const float4*)(p + 4);
        v[0]=a.x; v[1]=a.y; v[2]=a.z; v[3]=a.w;
        v[4]=b.x; v[5]=b.y; v[6]=b.z; v[7]=b.w;
    } else {
        #pragma unroll
        for (int j = 0; j < 8; ++j) v[j] = 0.f;
    }
    bf16x8 h, l;
    #pragma unroll
    for (int j = 0; j < 8; ++j) {
        short t = f2bf_t(v[j]);
        h[j] = t;
        l[j] = f2bf(v[j] - bf2f(t));
    }
    *(bf16x8*)&hi[(size_t)row * KPAD + k] = h;
    *(bf16x8*)&lo[(size_t)row * KPAD + k] = l;
}

// ---------------------------------------------------------------------------
// Split-bf16 MFMA GEMM: A converted in-kernel, B from pre-converted blob.
//   C[M x 768] = A[M x KREAL] @ Bblob[768 x KPAD]^T + [bias0;bias1]
// ---------------------------------------------------------------------------
#define GM_LDK 40

template<int KREAL, int KPAD, bool AVG>
__global__ __launch_bounds__(256, 2) void gemm_v3(
    const float* __restrict__ A0, const float* __restrict__ A1, int M,
    const short* __restrict__ Bhi_g, const short* __restrict__ Blo_g,
    const float* __restrict__ bias0, const float* __restrict__ bias1,
    float* __restrict__ C)
{
    const int ct = blockIdx.x;
    const int rt = blockIdx.y;
    const int tid = threadIdx.x;
    const int lane = tid & 63;
    const int wid  = tid >> 6;
    const int rlane = lane & 15;
    const int kgrp  = lane >> 4;

    const int rowBase = rt * 128;
    const int colBase = ct * 128;

    __shared__ short Ahi[128][GM_LDK], Alo[128][GM_LDK];
    __shared__ short Bhi[128][GM_LDK], Blo[128][GM_LDK];

    const int wrow = (wid >> 1) * 64;
    const int wcol = (wid & 1) * 64;

    f32x4 acc[4][4];
    #pragma unroll
    for (int i = 0; i < 4; ++i)
        #pragma unroll
        for (int j = 0; j < 4; ++j) acc[i][j] = {0.f, 0.f, 0.f, 0.f};

    const int srow = tid >> 1;
    const int skh  = (tid & 1) << 4;
    const size_t brow = (size_t)(colBase + srow) * KPAD;

    for (int k0 = 0; k0 < KPAD; k0 += 32) {
        // ---- stage A chunk (f32 -> split-bf16, in-kernel) ----
        {
            const int grow = rowBase + srow;
            float v[16];
            #pragma unroll
            for (int i = 0; i < 4; ++i) {
                const int k = k0 + skh + i * 4;
                float4 x = {0.f, 0.f, 0.f, 0.f};
                if (grow < M && k + 3 < KREAL) {
                    x = *(const float4*)&A0[(size_t)grow * KREAL + k];
                    if (AVG) {
                        float4 y = *(const float4*)&A1[(size_t)grow * KREAL + k];
                        x.x = 0.5f * (x.x + y.x); x.y = 0.5f * (x.y + y.y);
                        x.z = 0.5f * (x.z + y.z); x.w = 0.5f * (x.w + y.w);
                    }
                }
                v[4*i+0] = x.x; v[4*i+1] = x.y; v[4*i+2] = x.z; v[4*i+3] = x.w;
            }
            bf16x8 h0, h1, l0, l1;
            #pragma unroll
            for (int i = 0; i < 8; ++i) {
                short a = f2bf_t(v[i]);
                h0[i] = a; l0[i] = f2bf(v[i] - bf2f(a));
                short b = f2bf_t(v[i + 8]);
                h1[i] = b; l1[i] = f2bf(v[i + 8] - bf2f(b));
            }
            *(bf16x8*)&Ahi[srow][skh]     = h0;
            *(bf16x8*)&Ahi[srow][skh + 8] = h1;
            *(bf16x8*)&Alo[srow][skh]     = l0;
            *(bf16x8*)&Alo[srow][skh + 8] = l1;
        }
        // ---- stage B chunk (pre-converted: plain short8 loads) ----
        *(bf16x8*)&Bhi[srow][skh]     = *(const bf16x8*)&Bhi_g[brow + k0 + skh];
        *(bf16x8*)&Bhi[srow][skh + 8] = *(const bf16x8*)&Bhi_g[brow + k0 + skh + 8];
        *(bf16x8*)&Blo[srow][skh]     = *(const bf16x8*)&Blo_g[brow + k0 + skh];
        *(bf16x8*)&Blo[srow][skh + 8] = *(const bf16x8*)&Blo_g[brow + k0 + skh + 8];
        __syncthreads();
        bf16x8 ah[4], al[4], bh[4], bl[4];
        #pragma unroll
        for (int mr = 0; mr < 4; ++mr) {
            ah[mr] = *(const bf16x8*)&Ahi[wrow + mr * 16 + rlane][kgrp * 8];
            al[mr] = *(const bf16x8*)&Alo[wrow + mr * 16 + rlane][kgrp * 8];
        }
        #pragma unroll
        for (int nc = 0; nc < 4; ++nc) {
            bh[nc] = *(const bf16x8*)&Bhi[wcol + nc * 16 + rlane][kgrp * 8];
            bl[nc] = *(const bf16x8*)&Blo[wcol + nc * 16 + rlane][kgrp * 8];
        }
        #pragma unroll
        for (int mr = 0; mr < 4; ++mr)
            #pragma unroll
            for (int nc = 0; nc < 4; ++nc) {
                acc[mr][nc] = __builtin_amdgcn_mfma_f32_16x16x32_bf16(
                    ah[mr], bh[nc], acc[mr][nc], 0, 0, 0);
                acc[mr][nc] = __builtin_amdgcn_mfma_f32_16x16x32_bf16(
                    ah[mr], bl[nc], acc[mr][nc], 0, 0, 0);
                acc[mr][nc] = __builtin_amdgcn_mfma_f32_16x16x32_bf16(
                    al[mr], bh[nc], acc[mr][nc], 0, 0, 0);
            }
        __syncthreads();
    }

    const float* bs = (colBase < G3) ? bias0 : bias1;
    const int bcol = (colBase < G3) ? colBase : (colBase - G3);
    #pragma unroll
    for (int nc = 0; nc < 4; ++nc) {
        const int c = wcol + nc * 16 + rlane;
        const float bv = bs[bcol + c];
        #pragma unroll
        for (int mr = 0; mr < 4; ++mr) {
            #pragma unroll
            for (int r = 0; r < 4; ++r) {
                const int grow = rowBase + wrow + mr * 16 + kgrp * 4 + r;
                if (grow < M)
                    C[(size_t)grow * NPROJ + colBase + c] = acc[mr][nc][r] + bv;
            }
        }
    }
}

// ---------------------------------------------------------------------------
// Single-block counting sort for BOTH length arrays.
// ---------------------------------------------------------------------------
__global__ __launch_bounds__(256) void sort_all(
    const int* __restrict__ len1, int* __restrict__ order1,
    const int* __restrict__ len2, int* __restrict__ order2)
{
    __shared__ int hist[65];
    const int tid = threadIdx.x;

    for (int i = tid; i < 65; i += 256) hist[i] = 0;
    __syncthreads();
    for (int i = tid; i < NSENT; i += 256) atomicAdd(&hist[len1[i]], 1);
    __syncthreads();
    if (tid == 0) {
        int acc = 0;
        for (int l = 1; l <= WW; ++l) { int c = hist[l]; hist[l] = acc; acc += c; }
    }
    __syncthreads();
    for (int i = tid; i < NSENT; i += 256) {
        int pos = atomicAdd(&hist[len1[i]], 1);
        order1[pos] = i;
    }
    __syncthreads();
    for (int i = tid; i < 65; i += 256) hist[i] = 0;
    __syncthreads();
    for (int i = tid; i < NREV; i += 256) atomicAdd(&hist[len2[i]], 1);
    __syncthreads();
    if (tid == 0) {
        int acc = 0;
        for (int l = 1; l <= SS; ++l) { int c = hist[l]; hist[l] = acc; acc += c; }
    }
    __syncthreads();
    for (int i = tid; i < NREV; i += 256) {
        int pos = atomicAdd(&hist[len2[i]], 1);
        order2[pos] = i;
    }
}

// ---------------------------------------------------------------------------
// DUAL-STREAM MFMA GRU scan: one block = TWO independent tiles (same dir),
// sharing the 96-VGPR weight fragments. Per iteration both streams advance
// one step; stream B's MFMA issue hides stream A's accumulator latency (ILP
// inside the barrier-locked block — TLP across blocks is reg-capped at 1
// block/CU). Long tile paired with short tile for balance. Grid = numTiles
// (= 2 dirs x numTiles/2 blocks), all co-resident.
// ---------------------------------------------------------------------------
template<bool WORD, int TMAX>
__global__ __launch_bounds__(512, 2) void gru_dual(
    const float* __restrict__ table,
    const int*   __restrict__ tokens,
    const int*   __restrict__ lengths,
    const int*   __restrict__ order,
    const float* __restrict__ Whh_f, const float* __restrict__ Whh_b,
    const float* __restrict__ bhh_f, const float* __restrict__ bhh_b,
    float* __restrict__ hout_f, float* __restrict__ hout_b,
    int numSeq, int numTiles)
{
    const int halfT = numTiles >> 1;
    const int b = blockIdx.x;
    const int dir = (b >= halfT) ? 1 : 0;
    const int q = dir ? (b - halfT) : b;
    const int tileA = numTiles - 1 - q;   // long tile
    const int tileB = q;                  // short tile
    const int baseA = tileA * 16;
    const int baseB = tileB * 16;

    const int tid  = threadIdx.x;              // 0..511
    const int lane = tid & 63;
    const int wid  = tid >> 6;                 // 0..7
    const int rlane = lane & 15;
    const int kgrp  = lane >> 4;               // 0..3
    const int e = wid * 16 + rlane;

    __shared__ __align__(16) short shA_hi[2][16][136], shA_lo[2][16][136];
    __shared__ __align__(16) short shB_hi[2][16][136], shB_lo[2][16][136];
    __shared__ int shA_len[16], shA_ord[16], shB_len[16], shB_ord[16];
    __shared__ int shA_tok[WORD ? 16 * WW : 1];
    __shared__ int shB_tok[WORD ? 16 * WW : 1];
    __shared__ int sh_ml2[2];

    // ---- shared weight fragments (one dir for both streams) ----
    const float* Whh = dir ? Whh_b : Whh_f;
    const float* bhh = dir ? bhh_b : bhh_f;
    bf16x8 Bhi[3][4], Blo[3][4];
    float bb[3];
    #pragma unroll
    for (int nt = 0; nt < 3; ++nt) {
        const int cb = nt * HDIM + wid * 16;
        const float* wrow = Whh + (size_t)(cb + rlane) * HDIM;
        bb[nt] = bhh[cb + rlane];
        #pragma unroll
        for (int kc = 0; kc < 4; ++kc) {
            const float* wp = wrow + kc * 32 + kgrp * 8;
            float4 w0 = *(const float4*)wp;
            float4 w1 = *(const float4*)(wp + 4);
            float wv[8] = {w0.x, w0.y, w0.z, w0.w, w1.x, w1.y, w1.z, w1.w};
            #pragma unroll
            for (int j = 0; j < 8; ++j) {
                short hi = f2bf_t(wv[j]);
                Bhi[nt][kc][j] = hi;
                Blo[nt][kc][j] = f2bf(wv[j] - bf2f(hi));
            }
        }
    }

    // ---- tile metadata for both streams ----
    if (tid < 16) {
        int pos = baseA + tid;
        int seq = (pos < numSeq) ? order[pos] : -1;
        shA_ord[tid] = seq;
        shA_len[tid] = (seq >= 0) ? lengths[seq] : 0;
    } else if (tid < 32) {
        int u = tid - 16;
        int pos = baseB + u;
        int seq = (pos < numSeq) ? order[pos] : -1;
        shB_ord[u] = seq;
        shB_len[u] = (seq >= 0) ? lengths[seq] : 0;
    }
    __syncthreads();
    if (WORD) {
        for (int f = tid; f < 16 * WW; f += 512) {
            int s = f >> 6;
            int sa = shA_ord[s], sb = shB_ord[s];
            shA_tok[f] = (sa >= 0) ? tokens[(size_t)sa * WW + (f & 63)] : 0;
            shB_tok[f] = (sb >= 0) ? tokens[(size_t)sb * WW + (f & 63)] : 0;
        }
    }
    for (int u = tid; u < 2 * 16 * 136; u += 512) {
        ((short*)shA_hi)[u] = 0; ((short*)shA_lo)[u] = 0;
        ((short*)shB_hi)[u] = 0; ((short*)shB_lo)[u] = 0;
    }
    if (tid == 0) {
        int m = 0;
        for (int s = 0; s < 16; ++s) m = max(m, shA_len[s]);
        sh_ml2[0] = m;
    } else if (tid == 1) {
        int m = 0;
        for (int s = 0; s < 16; ++s) m = max(m, shB_len[s]);
        sh_ml2[1] = m;
    }
    int lensA[4], ordsA[4], lensB[4], ordsB[4];
    #pragma unroll
    for (int j = 0; j < 4; ++j) {
        lensA[j] = shA_len[4 * kgrp + j];
        ordsA[j] = shA_ord[4 * kgrp + j];
        lensB[j] = shB_len[4 * kgrp + j];
        ordsB[j] = shB_ord[4 * kgrp + j];
    }
    __syncthreads();
    const int mlA = sh_ml2[0];
    const int mlB = sh_ml2[1];
    const int maxt = max(mlA, mlB);

    auto fetchA = [&](int t, float* fr, float* fz, float* fn) {
        #pragma unroll
        for (int j = 0; j < 4; ++j) {
            fr[j] = 0.f; fz[j] = 0.f; fn[j] = 0.f;
            if (t < lensA[j]) {
                int tt = dir ? (lensA[j] - 1 - t) : t;
                size_t row;
                if (WORD) row = (size_t)shA_tok[(4 * kgrp + j) * WW + tt];
                else      row = (size_t)ordsA[j] * TMAX + tt;
                const float* xg = table + row * NPROJ + dir * G3 + e;
                fr[j] = xg[0]; fz[j] = xg[HDIM]; fn[j] = xg[2 * HDIM];
            }
        }
    };
    auto fetchB = [&](int t, float* fr, float* fz, float* fn) {
        #pragma unroll
        for (int j = 0; j < 4; ++j) {
            fr[j] = 0.f; fz[j] = 0.f; fn[j] = 0.f;
            if (t < lensB[j]) {
                int tt = dir ? (lensB[j] - 1 - t) : t;
                size_t row;
                if (WORD) row = (size_t)shB_tok[(4 * kgrp + j) * WW + tt];
                else      row = (size_t)ordsB[j] * TMAX + tt;
                const float* xg = table + row * NPROJ + dir * G3 + e;
                fr[j] = xg[0]; fz[j] = xg[HDIM]; fn[j] = xg[2 * HDIM];
            }
        }
    };

    float holdA[4] = {0.f, 0.f, 0.f, 0.f};
    float holdB[4] = {0.f, 0.f, 0.f, 0.f};
    float pAr[4], pAz[4], pAn[4];      // stream A, depth-1 prefetch
    float pBr[4], pBz[4], pBn[4];      // stream B
    fetchA(0, pAr, pAz, pAn);
    fetchB(0, pBr, pBz, pBn);

    for (int t = 0; t < maxt; ++t) {
        const int cur = t & 1, nxt = cur ^ 1;
        const bool actA = (t < mlA), actB = (t < mlB);   // block-uniform
        bf16x8 ahA[4], alA[4], ahB[4], alB[4];
        f32x4 accA[3], accB[3];
        if (actA) {
            #pragma unroll
            for (int kc = 0; kc < 4; ++kc) {
                ahA[kc] = *(const bf16x8*)&shA_hi[cur][rlane][kc * 32 + kgrp * 8];
                alA[kc] = *(const bf16x8*)&shA_lo[cur][rlane][kc * 32 + kgrp * 8];
            }
        }
        if (actB) {
            #pragma unroll
            for (int kc = 0; kc < 4; ++kc) {
                ahB[kc] = *(const bf16x8*)&shB_hi[cur][rlane][kc * 32 + kgrp * 8];
                alB[kc] = *(const bf16x8*)&shB_lo[cur][rlane][kc * 32 + kgrp * 8];
            }
        }
        if (actA) {
            #pragma unroll
            for (int nt = 0; nt < 3; ++nt) {
                accA[nt] = {0.f, 0.f, 0.f, 0.f};
                #pragma unroll
                for (int kc = 0; kc < 4; ++kc)
                    accA[nt] = __builtin_amdgcn_mfma_f32_16x16x32_bf16(
                        ahA[kc], Bhi[nt][kc], accA[nt], 0, 0, 0);
                #pragma unroll
                for (int kc = 0; kc < 4; ++kc)
                    accA[nt] = __builtin_amdgcn_mfma_f32_16x16x32_bf16(
                        ahA[kc], Blo[nt][kc], accA[nt], 0, 0, 0);
                #pragma unroll
                for (int kc = 0; kc < 4; ++kc)
                    accA[nt] = __builtin_amdgcn_mfma_f32_16x16x32_bf16(
                        alA[kc], Bhi[nt][kc], accA[nt], 0, 0, 0);
            }
        }
        if (actB) {
            #pragma unroll
            for (int nt = 0; nt < 3; ++nt) {
                accB[nt] = {0.f, 0.f, 0.f, 0.f};
                #pragma unroll
                for (int kc = 0; kc < 4; ++kc)
                    accB[nt] = __builtin_amdgcn_mfma_f32_16x16x32_bf16(
                        ahB[kc], Bhi[nt][kc], accB[nt], 0, 0, 0);
                #pragma unroll
                for (int kc = 0; kc < 4; ++kc)
                    accB[nt] = __builtin_amdgcn_mfma_f32_16x16x32_bf16(
                        ahB[kc], Blo[nt][kc], accB[nt], 0, 0, 0);
                #pragma unroll
                for (int kc = 0; kc < 4; ++kc)
                    accB[nt] = __builtin_amdgcn_mfma_f32_16x16x32_bf16(
                        alB[kc], Bhi[nt][kc], accB[nt], 0, 0, 0);
            }
        }
        if (actA) {
            #pragma unroll
            for (int j = 0; j < 4; ++j) {
                if (t < lensA[j]) {
                    float hgr = accA[0][j] + bb[0];
                    float hgz = accA[1][j] + bb[1];
                    float hgn = accA[2][j] + bb[2];
                    float rg = fsigmoid(pAr[j] + hgr);
                    float zg = fsigmoid(pAz[j] + hgz);
                    float ng = ftanh(pAn[j] + rg * hgn);
                    holdA[j] = (1.f - zg) * ng + zg * holdA[j];
                }
            }
            fetchA(t + 1, pAr, pAz, pAn);
            #pragma unroll
            for (int j = 0; j < 4; ++j) {
                const int s = 4 * kgrp + j;
                short hi = f2bf_t(holdA[j]);
                shA_hi[nxt][s][e] = hi;
                shA_lo[nxt][s][e] = f2bf(holdA[j] - bf2f(hi));
            }
        }
        if (actB) {
            #pragma unroll
            for (int j = 0; j < 4; ++j) {
                if (t < lensB[j]) {
                    float hgr = accB[0][j] + bb[0];
                    float hgz = accB[1][j] + bb[1];
                    float hgn = accB[2][j] + bb[2];
                    float rg = fsigmoid(pBr[j] + hgr);
                    float zg = fsigmoid(pBz[j] + hgz);
                    float ng = ftanh(pBn[j] + rg * hgn);
                    holdB[j] = (1.f - zg) * ng + zg * holdB[j];
                }
            }
            fetchB(t + 1, pBr, pBz, pBn);
            #pragma unroll
            for (int j = 0; j < 4; ++j) {
                const int s = 4 * kgrp + j;
                short hi = f2bf_t(holdB[j]);
                shB_hi[nxt][s][e] = hi;
                shB_lo[nxt][s][e] = f2bf(holdB[j] - bf2f(hi));
            }
        }
        __syncthreads();
    }

    // ---- write out last-h for both streams ----
    float* hout = dir ? hout_b : hout_f;
    #pragma unroll
    for (int j = 0; j < 4; ++j) {
        if (ordsA[j] >= 0) hout[(size_t)ordsA[j] * HDIM + e] = holdA[j];
        if (ordsB[j] >= 0) hout[(size_t)ordsB[j] * HDIM + e] = holdB[j];
    }
}

// ---------------------------------------------------------------------------
// Head + mean
// ---------------------------------------------------------------------------
__global__ __launch_bounds__(64) void head_kernel(
    const float* __restrict__ hsf, const float* __restrict__ hsb,
    const float* __restrict__ fc1_w, const float* __restrict__ fc1_b,
    const float* __restrict__ fc2_w, const float* __restrict__ fc2_b,
    float* __restrict__ out)
{
    const int br = blockIdx.x;
    const int j = threadIdx.x;
    __shared__ float rev[HDIM];
    for (int ee = j; ee < HDIM; ee += 64)
        rev[ee] = 0.5f * (hsf[(size_t)br * HDIM + ee] + hsb[(size_t)br * HDIM + ee]);
    __syncthreads();
    float acc = 0.f;
    #pragma unroll
    for (int k = 0; k < HDIM; ++k)
        acc = fmaf(fc1_w[(size_t)j * HDIM + k], rev[k], acc);
    acc += fc1_b[j];
    const float alpha = 1.6732632423543772f;
    const float scale = 1.0507009873554805f;
    float h1 = scale * (acc > 0.f ? acc : alpha * (expf(acc) - 1.f));
    float contrib = h1 * fc2_w[j];
    #pragma unroll
    for (int off = 32; off > 0; off >>= 1)
        contrib += __shfl_down(contrib, off);
    if (j == 0) out[16 + br] = contrib + fc2_b[0];
}

__global__ void mean_kernel(float* __restrict__ out)
{
    int b = threadIdx.x;
    if (b < BB) {
        float s = 0.f;
        for (int r = 0; r < RR; ++r) s += out[16 + b * RR + r];
        out[b] = s / (float)RR;
    }
}

// ---------------------------------------------------------------------------
// Launch
// ---------------------------------------------------------------------------
extern "C" void kernel_launch(void* const* d_in, const int* in_sizes, int n_in,
                              void* d_out, int out_size, void* d_ws, size_t ws_size,
                              hipStream_t stream)
{
    const int*   inputs       = (const int*)d_in[0];
    const int*   sent_lengths = (const int*)d_in[1];
    const int*   sent_counts  = (const int*)d_in[2];
    const float* embed   = (const float*)d_in[3];
    const float* wWih_f  = (const float*)d_in[4];
    const float* wWhh_f  = (const float*)d_in[5];
    const float* wbih_f  = (const float*)d_in[6];
    const float* wbhh_f  = (const float*)d_in[7];
    const float* wWih_b  = (const float*)d_in[8];
    const float* wWhh_b  = (const float*)d_in[9];
    const float* wbih_b  = (const float*)d_in[10];
    const float* wbhh_b  = (const float*)d_in[11];
    const float* sWih_f  = (const float*)d_in[12];
    const float* sWhh_f  = (const float*)d_in[13];
    const float* sbih_f  = (const float*)d_in[14];
    const float* sbhh_f  = (const float*)d_in[15];
    const float* sWih_b  = (const float*)d_in[16];
    const float* sWhh_b  = (const float*)d_in[17];
    const float* sbih_b  = (const float*)d_in[18];
    const float* sbhh_b  = (const float*)d_in[19];
    const float* fc1_w   = (const float*)d_in[20];
    const float* fc1_b   = (const float*)d_in[21];
    const float* fc2_w   = (const float*)d_in[22];
    const float* fc2_b   = (const float*)d_in[23];

    float* ws = (float*)d_ws;
    const size_t projT_elems = (size_t)VOCAB * NPROJ;      // 38,400,000
    const size_t xgs_elems   = (size_t)NSENT * NPROJ;      //  2,457,600
    const size_t h_elems     = (size_t)NSENT * HDIM;       //    409,600
    const size_t hs_elems    = (size_t)NREV * HDIM;        //     20,480
    float* projT = ws;
    float* xgs   = projT + projT_elems;
    float* hf    = xgs + xgs_elems;
    float* hb    = hf + h_elems;
    float* hsf   = hb + h_elems;
    float* hsb   = hsf + hs_elems;
    int* order1  = (int*)(hsb + hs_elems);         // [NSENT]
    int* order2  = order1 + NSENT;                 // [NREV]
    short* Bw_hi = (short*)(order2 + NREV);        // [768*224]
    short* Bw_lo = Bw_hi + 768 * 224;
    short* Sw_hi = Bw_lo + 768 * 224;              // [768*128]
    short* Sw_lo = Sw_hi + 768 * 128;

    size_t need = (projT_elems + xgs_elems + 2*h_elems + 2*hs_elems) * sizeof(float)
                + (NSENT + NREV) * sizeof(int)
                + (size_t)(2 * 768 * 224 + 2 * 768 * 128) * sizeof(short);
    if (ws_size < need) return;

    // 0) counting sort + weight-blob preconversion (all tiny)
    sort_all<<<1, 256, 0, stream>>>(sent_lengths, order1, sent_counts, order2);
    {
        int ng = 384 * 224 / 8;
        preconv<EDIM, 224><<<(ng + 255) / 256, 256, 0, stream>>>(
            wWih_f, 384, Bw_hi, Bw_lo, ng);
        preconv<EDIM, 224><<<(ng + 255) / 256, 256, 0, stream>>>(
            wWih_b, 384, Bw_hi + 384 * 224, Bw_lo + 384 * 224, ng);
    }
    {
        int ng = 384 * 128 / 8;
        preconv<HDIM, HDIM><<<(ng + 255) / 256, 256, 0, stream>>>(
            sWih_f, 384, Sw_hi, Sw_lo, ng);
        preconv<HDIM, HDIM><<<(ng + 255) / 256, 256, 0, stream>>>(
            sWih_b, 384, Sw_hi + 384 * 128, Sw_lo + 384 * 128, ng);
    }

    // 1) projected-embedding table (A converted in-kernel, B from blob)
    {
        dim3 grid(NPROJ / 128, (VOCAB + 127) / 128);    // 6 x 391
        gemm_v3<EDIM, 224, false><<<grid, 256, 0, stream>>>(
            embed, nullptr, VOCAB, Bw_hi, Bw_lo, wbih_f, wbih_b, projT);
    }
    // 2) word-level BiGRU last-h (dual-stream scan; grid = 200, all resident)
    {
        int numTiles = NSENT / 16;                      // 200 (even)
        gru_dual<true, WW><<<numTiles, 512, 0, stream>>>(
            projT, inputs, sent_lengths, order1,
            wWhh_f, wWhh_b, wbhh_f, wbhh_b,
            hf, hb, NSENT, numTiles);
    }
    // 3) sentence-level input projections
    {
        dim3 grid(NPROJ / 128, (NSENT + 127) / 128);    // 6 x 25
        gemm_v3<HDIM, HDIM, true><<<grid, 256, 0, stream>>>(
            hf, hb, NSENT, Sw_hi, Sw_lo, sbih_f, sbih_b, xgs);
    }
    // 4) sentence-level BiGRU last-h (dual-stream scan; grid = 10)
    {
        int numTiles = NREV / 16;                       // 10 (even)
        gru_dual<false, SS><<<numTiles, 512, 0, stream>>>(
            xgs, nullptr, sent_counts, order2,
            sWhh_f, sWhh_b, sbhh_f, sbhh_b,
            hsf, hsb, NREV, numTiles);
    }
    // 5) FC head -> r_stars, then p_stars
    head_kernel<<<NREV, 64, 0, stream>>>(hsf, hsb, fc1_w, fc1_b, fc2_w, fc2_b,
                                         (float*)d_out);
    mean_kernel<<<1, 64, 0, stream>>>((float*)d_out);
}

// Round 15
// 294.362 us; speedup vs baseline: 1.0619x; 1.0619x over previous
//
#include <hip/hip_runtime.h>
#include <hip/hip_bf16.h>
#include <cstddef>

// ---------------------------------------------------------------------------
// Problem dims
// ---------------------------------------------------------------------------
#define VOCAB 50000
#define EDIM  200
#define HDIM  128
#define BB 16
#define RR 10
#define SS 20
#define WW 64
#define NSENT (BB*RR*SS)   // 3200 word-level sequences
#define NREV  (BB*RR)      // 160 sentence-level sequences
#define G3    (3*HDIM)     // 384 gate rows per direction
#define NPROJ (2*G3)       // 768

// ---------------------------------------------------------------------------
// bf16 + fast-math helpers
// ---------------------------------------------------------------------------
static __device__ __forceinline__ short f2bf(float f) {    // RNE (for lo parts)
    union { float f; unsigned u; } v; v.f = f;
    unsigned r = v.u + 0x7FFFu + ((v.u >> 16) & 1u);
    return (short)(r >> 16);
}
static __device__ __forceinline__ short f2bf_t(float f) {  // truncate (hi parts)
    union { float f; unsigned u; } v; v.f = f;
    return (short)(v.u >> 16);
}
static __device__ __forceinline__ float bf2f(short s) {
    union { unsigned u; float f; } v;
    v.u = ((unsigned)(unsigned short)s) << 16;
    return v.f;
}
static __device__ __forceinline__ float frcp(float x) {
    return __builtin_amdgcn_rcpf(x);
}
static __device__ __forceinline__ float fsigmoid(float x) {
    return frcp(1.f + __expf(-x));
}
static __device__ __forceinline__ float ftanh(float x) {
    float y = __expf(-2.f * fabsf(x));
    float t = (1.f - y) * frcp(1.f + y);
    return copysignf(t, x);
}

using bf16x8 = __attribute__((ext_vector_type(8))) short;
using f32x4  = __attribute__((ext_vector_type(4))) float;

// ---------------------------------------------------------------------------
// preconv: f32 [.][KREAL] -> split-bf16 [.][KPAD] blobs (weights only).
// ---------------------------------------------------------------------------
template<int KREAL, int KPAD>
__global__ __launch_bounds__(256) void preconv(
    const float* __restrict__ A0, int Mreal,
    short* __restrict__ hi, short* __restrict__ lo, int ngroups)
{
    int g = blockIdx.x * 256 + threadIdx.x;
    if (g >= ngroups) return;
    int row = g / (KPAD / 8);
    int k   = (g % (KPAD / 8)) * 8;
    float v[8];
    if (row < Mreal && k < KREAL) {
        const float* p = A0 + (size_t)row * KREAL + k;
        float4 a = *(const float4*)p;
        float4 b = *(const float4*)(p + 4);
        v[0]=a.x; v[1]=a.y; v[2]=a.z; v[3]=a.w;
        v[4]=b.x; v[5]=b.y; v[6]=b.z; v[7]=b.w;
    } else {
        #pragma unroll
        for (int j = 0; j < 8; ++j) v[j] = 0.f;
    }
    bf16x8 h, l;
    #pragma unroll
    for (int j = 0; j < 8; ++j) {
        short t = f2bf_t(v[j]);
        h[j] = t;
        l[j] = f2bf(v[j] - bf2f(t));
    }
    *(bf16x8*)&hi[(size_t)row * KPAD + k] = h;
    *(bf16x8*)&lo[(size_t)row * KPAD + k] = l;
}

// ---------------------------------------------------------------------------
// Split-bf16 MFMA GEMM: A converted in-kernel, B from pre-converted blob.
// ---------------------------------------------------------------------------
#define GM_LDK 40

template<int KREAL, int KPAD, bool AVG>
__global__ __launch_bounds__(256, 2) void gemm_v3(
    const float* __restrict__ A0, const float* __restrict__ A1, int M,
    const short* __restrict__ Bhi_g, const short* __restrict__ Blo_g,
    const float* __restrict__ bias0, const float* __restrict__ bias1,
    float* __restrict__ C)
{
    const int ct = blockIdx.x;
    const int rt = blockIdx.y;
    const int tid = threadIdx.x;
    const int lane = tid & 63;
    const int wid  = tid >> 6;
    const int rlane = lane & 15;
    const int kgrp  = lane >> 4;

    const int rowBase = rt * 128;
    const int colBase = ct * 128;

    __shared__ short Ahi[128][GM_LDK], Alo[128][GM_LDK];
    __shared__ short Bhi[128][GM_LDK], Blo[128][GM_LDK];

    const int wrow = (wid >> 1) * 64;
    const int wcol = (wid & 1) * 64;

    f32x4 acc[4][4];
    #pragma unroll
    for (int i = 0; i < 4; ++i)
        #pragma unroll
        for (int j = 0; j < 4; ++j) acc[i][j] = {0.f, 0.f, 0.f, 0.f};

    const int srow = tid >> 1;
    const int skh  = (tid & 1) << 4;
    const size_t brow = (size_t)(colBase + srow) * KPAD;

    for (int k0 = 0; k0 < KPAD; k0 += 32) {
        {
            const int grow = rowBase + srow;
            float v[16];
            #pragma unroll
            for (int i = 0; i < 4; ++i) {
                const int k = k0 + skh + i * 4;
                float4 x = {0.f, 0.f, 0.f, 0.f};
                if (grow < M && k + 3 < KREAL) {
                    x = *(const float4*)&A0[(size_t)grow * KREAL + k];
                    if (AVG) {
                        float4 y = *(const float4*)&A1[(size_t)grow * KREAL + k];
                        x.x = 0.5f * (x.x + y.x); x.y = 0.5f * (x.y + y.y);
                        x.z = 0.5f * (x.z + y.z); x.w = 0.5f * (x.w + y.w);
                    }
                }
                v[4*i+0] = x.x; v[4*i+1] = x.y; v[4*i+2] = x.z; v[4*i+3] = x.w;
            }
            bf16x8 h0, h1, l0, l1;
            #pragma unroll
            for (int i = 0; i < 8; ++i) {
                short a = f2bf_t(v[i]);
                h0[i] = a; l0[i] = f2bf(v[i] - bf2f(a));
                short b = f2bf_t(v[i + 8]);
                h1[i] = b; l1[i] = f2bf(v[i + 8] - bf2f(b));
            }
            *(bf16x8*)&Ahi[srow][skh]     = h0;
            *(bf16x8*)&Ahi[srow][skh + 8] = h1;
            *(bf16x8*)&Alo[srow][skh]     = l0;
            *(bf16x8*)&Alo[srow][skh + 8] = l1;
        }
        *(bf16x8*)&Bhi[srow][skh]     = *(const bf16x8*)&Bhi_g[brow + k0 + skh];
        *(bf16x8*)&Bhi[srow][skh + 8] = *(const bf16x8*)&Bhi_g[brow + k0 + skh + 8];
        *(bf16x8*)&Blo[srow][skh]     = *(const bf16x8*)&Blo_g[brow + k0 + skh];
        *(bf16x8*)&Blo[srow][skh + 8] = *(const bf16x8*)&Blo_g[brow + k0 + skh + 8];
        __syncthreads();
        bf16x8 ah[4], al[4], bh[4], bl[4];
        #pragma unroll
        for (int mr = 0; mr < 4; ++mr) {
            ah[mr] = *(const bf16x8*)&Ahi[wrow + mr * 16 + rlane][kgrp * 8];
            al[mr] = *(const bf16x8*)&Alo[wrow + mr * 16 + rlane][kgrp * 8];
        }
        #pragma unroll
        for (int nc = 0; nc < 4; ++nc) {
            bh[nc] = *(const bf16x8*)&Bhi[wcol + nc * 16 + rlane][kgrp * 8];
            bl[nc] = *(const bf16x8*)&Blo[wcol + nc * 16 + rlane][kgrp * 8];
        }
        #pragma unroll
        for (int mr = 0; mr < 4; ++mr)
            #pragma unroll
            for (int nc = 0; nc < 4; ++nc) {
                acc[mr][nc] = __builtin_amdgcn_mfma_f32_16x16x32_bf16(
                    ah[mr], bh[nc], acc[mr][nc], 0, 0, 0);
                acc[mr][nc] = __builtin_amdgcn_mfma_f32_16x16x32_bf16(
                    ah[mr], bl[nc], acc[mr][nc], 0, 0, 0);
                acc[mr][nc] = __builtin_amdgcn_mfma_f32_16x16x32_bf16(
                    al[mr], bh[nc], acc[mr][nc], 0, 0, 0);
            }
        __syncthreads();
    }

    const float* bs = (colBase < G3) ? bias0 : bias1;
    const int bcol = (colBase < G3) ? colBase : (colBase - G3);
    #pragma unroll
    for (int nc = 0; nc < 4; ++nc) {
        const int c = wcol + nc * 16 + rlane;
        const float bv = bs[bcol + c];
        #pragma unroll
        for (int mr = 0; mr < 4; ++mr) {
            #pragma unroll
            for (int r = 0; r < 4; ++r) {
                const int grow = rowBase + wrow + mr * 16 + kgrp * 4 + r;
                if (grow < M)
                    C[(size_t)grow * NPROJ + colBase + c] = acc[mr][nc][r] + bv;
            }
        }
    }
}

// ---------------------------------------------------------------------------
// Single-block counting sort for BOTH length arrays.
// ---------------------------------------------------------------------------
__global__ __launch_bounds__(256) void sort_all(
    const int* __restrict__ len1, int* __restrict__ order1,
    const int* __restrict__ len2, int* __restrict__ order2)
{
    __shared__ int hist[65];
    const int tid = threadIdx.x;

    for (int i = tid; i < 65; i += 256) hist[i] = 0;
    __syncthreads();
    for (int i = tid; i < NSENT; i += 256) atomicAdd(&hist[len1[i]], 1);
    __syncthreads();
    if (tid == 0) {
        int acc = 0;
        for (int l = 1; l <= WW; ++l) { int c = hist[l]; hist[l] = acc; acc += c; }
    }
    __syncthreads();
    for (int i = tid; i < NSENT; i += 256) {
        int pos = atomicAdd(&hist[len1[i]], 1);
        order1[pos] = i;
    }
    __syncthreads();
    for (int i = tid; i < 65; i += 256) hist[i] = 0;
    __syncthreads();
    for (int i = tid; i < NREV; i += 256) atomicAdd(&hist[len2[i]], 1);
    __syncthreads();
    if (tid == 0) {
        int acc = 0;
        for (int l = 1; l <= SS; ++l) { int c = hist[l]; hist[l] = acc; acc += c; }
    }
    __syncthreads();
    for (int i = tid; i < NREV; i += 256) {
        int pos = atomicAdd(&hist[len2[i]], 1);
        order2[pos] = i;
    }
}

// ---------------------------------------------------------------------------
// DUAL-STREAM MFMA GRU scan, launch_bounds(512,1): 256-VGPR budget so the
// ~230-reg dual state FITS (round-14 used (512,2) -> 128-reg cap -> spill).
// One block = TWO independent tiles (same dir) sharing the 96-VGPR weight
// fragments; per iteration both streams advance one step (2x work per
// barrier). Frag loads sequenced A-frags->MFMA-A->B-frags->MFMA-B to cap
// simultaneous liveness. Long+short tile pairing for balance.
// ---------------------------------------------------------------------------
template<bool WORD, int TMAX>
__global__ __launch_bounds__(512, 1) void gru_dual(
    const float* __restrict__ table,
    const int*   __restrict__ tokens,
    const int*   __restrict__ lengths,
    const int*   __restrict__ order,
    const float* __restrict__ Whh_f, const float* __restrict__ Whh_b,
    const float* __restrict__ bhh_f, const float* __restrict__ bhh_b,
    float* __restrict__ hout_f, float* __restrict__ hout_b,
    int numSeq, int numTiles)
{
    const int halfT = numTiles >> 1;
    const int b = blockIdx.x;
    const int dir = (b >= halfT) ? 1 : 0;
    const int q = dir ? (b - halfT) : b;
    const int tileA = numTiles - 1 - q;   // long tile
    const int tileB = q;                  // short tile
    const int baseA = tileA * 16;
    const int baseB = tileB * 16;

    const int tid  = threadIdx.x;              // 0..511
    const int lane = tid & 63;
    const int wid  = tid >> 6;                 // 0..7
    const int rlane = lane & 15;
    const int kgrp  = lane >> 4;               // 0..3
    const int e = wid * 16 + rlane;

    __shared__ __align__(16) short shA_hi[2][16][136], shA_lo[2][16][136];
    __shared__ __align__(16) short shB_hi[2][16][136], shB_lo[2][16][136];
    __shared__ int shA_len[16], shA_ord[16], shB_len[16], shB_ord[16];
    __shared__ int shA_tok[WORD ? 16 * WW : 1];
    __shared__ int shB_tok[WORD ? 16 * WW : 1];
    __shared__ int sh_ml2[2];

    // ---- shared weight fragments (one dir for both streams) ----
    const float* Whh = dir ? Whh_b : Whh_f;
    const float* bhh = dir ? bhh_b : bhh_f;
    bf16x8 Bhi[3][4], Blo[3][4];
    float bb[3];
    #pragma unroll
    for (int nt = 0; nt < 3; ++nt) {
        const int cb = nt * HDIM + wid * 16;
        const float* wrow = Whh + (size_t)(cb + rlane) * HDIM;
        bb[nt] = bhh[cb + rlane];
        #pragma unroll
        for (int kc = 0; kc < 4; ++kc) {
            const float* wp = wrow + kc * 32 + kgrp * 8;
            float4 w0 = *(const float4*)wp;
            float4 w1 = *(const float4*)(wp + 4);
            float wv[8] = {w0.x, w0.y, w0.z, w0.w, w1.x, w1.y, w1.z, w1.w};
            #pragma unroll
            for (int j = 0; j < 8; ++j) {
                short hi = f2bf_t(wv[j]);
                Bhi[nt][kc][j] = hi;
                Blo[nt][kc][j] = f2bf(wv[j] - bf2f(hi));
            }
        }
    }

    // ---- tile metadata for both streams ----
    if (tid < 16) {
        int pos = baseA + tid;
        int seq = (pos < numSeq) ? order[pos] : -1;
        shA_ord[tid] = seq;
        shA_len[tid] = (seq >= 0) ? lengths[seq] : 0;
    } else if (tid < 32) {
        int u = tid - 16;
        int pos = baseB + u;
        int seq = (pos < numSeq) ? order[pos] : -1;
        shB_ord[u] = seq;
        shB_len[u] = (seq >= 0) ? lengths[seq] : 0;
    }
    __syncthreads();
    if (WORD) {
        for (int f = tid; f < 16 * WW; f += 512) {
            int s = f >> 6;
            int sa = shA_ord[s], sb = shB_ord[s];
            shA_tok[f] = (sa >= 0) ? tokens[(size_t)sa * WW + (f & 63)] : 0;
            shB_tok[f] = (sb >= 0) ? tokens[(size_t)sb * WW + (f & 63)] : 0;
        }
    }
    for (int u = tid; u < 2 * 16 * 136; u += 512) {
        ((short*)shA_hi)[u] = 0; ((short*)shA_lo)[u] = 0;
        ((short*)shB_hi)[u] = 0; ((short*)shB_lo)[u] = 0;
    }
    if (tid == 0) {
        int m = 0;
        for (int s = 0; s < 16; ++s) m = max(m, shA_len[s]);
        sh_ml2[0] = m;
    } else if (tid == 1) {
        int m = 0;
        for (int s = 0; s < 16; ++s) m = max(m, shB_len[s]);
        sh_ml2[1] = m;
    }
    int lensA[4], ordsA[4], lensB[4], ordsB[4];
    #pragma unroll
    for (int j = 0; j < 4; ++j) {
        lensA[j] = shA_len[4 * kgrp + j];
        ordsA[j] = shA_ord[4 * kgrp + j];
        lensB[j] = shB_len[4 * kgrp + j];
        ordsB[j] = shB_ord[4 * kgrp + j];
    }
    __syncthreads();
    const int mlA = sh_ml2[0];
    const int mlB = sh_ml2[1];
    const int maxt = max(mlA, mlB);

    auto fetchA = [&](int t, float* fr, float* fz, float* fn) {
        #pragma unroll
        for (int j = 0; j < 4; ++j) {
            fr[j] = 0.f; fz[j] = 0.f; fn[j] = 0.f;
            if (t < lensA[j]) {
                int tt = dir ? (lensA[j] - 1 - t) : t;
                size_t row;
                if (WORD) row = (size_t)shA_tok[(4 * kgrp + j) * WW + tt];
                else      row = (size_t)ordsA[j] * TMAX + tt;
                const float* xg = table + row * NPROJ + dir * G3 + e;
                fr[j] = xg[0]; fz[j] = xg[HDIM]; fn[j] = xg[2 * HDIM];
            }
        }
    };
    auto fetchB = [&](int t, float* fr, float* fz, float* fn) {
        #pragma unroll
        for (int j = 0; j < 4; ++j) {
            fr[j] = 0.f; fz[j] = 0.f; fn[j] = 0.f;
            if (t < lensB[j]) {
                int tt = dir ? (lensB[j] - 1 - t) : t;
                size_t row;
                if (WORD) row = (size_t)shB_tok[(4 * kgrp + j) * WW + tt];
                else      row = (size_t)ordsB[j] * TMAX + tt;
                const float* xg = table + row * NPROJ + dir * G3 + e;
                fr[j] = xg[0]; fz[j] = xg[HDIM]; fn[j] = xg[2 * HDIM];
            }
        }
    };

    float holdA[4] = {0.f, 0.f, 0.f, 0.f};
    float holdB[4] = {0.f, 0.f, 0.f, 0.f};
    float pAr[4], pAz[4], pAn[4];      // stream A, depth-1 loop-carried
    float pBr[4], pBz[4], pBn[4];      // stream B
    fetchA(0, pAr, pAz, pAn);
    fetchB(0, pBr, pBz, pBn);

    for (int t = 0; t < maxt; ++t) {
        const int cur = t & 1, nxt = cur ^ 1;
        const bool actA = (t < mlA), actB = (t < mlB);   // block-uniform
        f32x4 accA[3], accB[3];
        // ---- stream A: frags + MFMA (B frags not yet live) ----
        if (actA) {
            bf16x8 ahA[4], alA[4];
            #pragma unroll
            for (int kc = 0; kc < 4; ++kc) {
                ahA[kc] = *(const bf16x8*)&shA_hi[cur][rlane][kc * 32 + kgrp * 8];
                alA[kc] = *(const bf16x8*)&shA_lo[cur][rlane][kc * 32 + kgrp * 8];
            }
            #pragma unroll
            for (int nt = 0; nt < 3; ++nt) {
                accA[nt] = {0.f, 0.f, 0.f, 0.f};
                #pragma unroll
                for (int kc = 0; kc < 4; ++kc)
                    accA[nt] = __builtin_amdgcn_mfma_f32_16x16x32_bf16(
                        ahA[kc], Bhi[nt][kc], accA[nt], 0, 0, 0);
                #pragma unroll
                for (int kc = 0; kc < 4; ++kc)
                    accA[nt] = __builtin_amdgcn_mfma_f32_16x16x32_bf16(
                        ahA[kc], Blo[nt][kc], accA[nt], 0, 0, 0);
                #pragma unroll
                for (int kc = 0; kc < 4; ++kc)
                    accA[nt] = __builtin_amdgcn_mfma_f32_16x16x32_bf16(
                        alA[kc], Bhi[nt][kc], accA[nt], 0, 0, 0);
            }
        }
        // ---- stream B: frags + MFMA (issues while A's acc chain drains) ----
        if (actB) {
            bf16x8 ahB[4], alB[4];
            #pragma unroll
            for (int kc = 0; kc < 4; ++kc) {
                ahB[kc] = *(const bf16x8*)&shB_hi[cur][rlane][kc * 32 + kgrp * 8];
                alB[kc] = *(const bf16x8*)&shB_lo[cur][rlane][kc * 32 + kgrp * 8];
            }
            #pragma unroll
            for (int nt = 0; nt < 3; ++nt) {
                accB[nt] = {0.f, 0.f, 0.f, 0.f};
                #pragma unroll
                for (int kc = 0; kc < 4; ++kc)
                    accB[nt] = __builtin_amdgcn_mfma_f32_16x16x32_bf16(
                        ahB[kc], Bhi[nt][kc], accB[nt], 0, 0, 0);
                #pragma unroll
                for (int kc = 0; kc < 4; ++kc)
                    accB[nt] = __builtin_amdgcn_mfma_f32_16x16x32_bf16(
                        ahB[kc], Blo[nt][kc], accB[nt], 0, 0, 0);
                #pragma unroll
                for (int kc = 0; kc < 4; ++kc)
                    accB[nt] = __builtin_amdgcn_mfma_f32_16x16x32_bf16(
                        alB[kc], Bhi[nt][kc], accB[nt], 0, 0, 0);
            }
        }
        // ---- gates + publish (A's acc wait covered by B's MFMA issue) ----
        if (actA) {
            #pragma unroll
            for (int j = 0; j < 4; ++j) {
                if (t < lensA[j]) {
                    float hgr = accA[0][j] + bb[0];
                    float hgz = accA[1][j] + bb[1];
                    float hgn = accA[2][j] + bb[2];
                    float rg = fsigmoid(pAr[j] + hgr);
                    float zg = fsigmoid(pAz[j] + hgz);
                    float ng = ftanh(pAn[j] + rg * hgn);
                    holdA[j] = (1.f - zg) * ng + zg * holdA[j];
                }
            }
            fetchA(t + 1, pAr, pAz, pAn);
            #pragma unroll
            for (int j = 0; j < 4; ++j) {
                const int s = 4 * kgrp + j;
                short hi = f2bf_t(holdA[j]);
                shA_hi[nxt][s][e] = hi;
                shA_lo[nxt][s][e] = f2bf(holdA[j] - bf2f(hi));
            }
        }
        if (actB) {
            #pragma unroll
            for (int j = 0; j < 4; ++j) {
                if (t < lensB[j]) {
                    float hgr = accB[0][j] + bb[0];
                    float hgz = accB[1][j] + bb[1];
                    float hgn = accB[2][j] + bb[2];
                    float rg = fsigmoid(pBr[j] + hgr);
                    float zg = fsigmoid(pBz[j] + hgz);
                    float ng = ftanh(pBn[j] + rg * hgn);
                    holdB[j] = (1.f - zg) * ng + zg * holdB[j];
                }
            }
            fetchB(t + 1, pBr, pBz, pBn);
            #pragma unroll
            for (int j = 0; j < 4; ++j) {
                const int s = 4 * kgrp + j;
                short hi = f2bf_t(holdB[j]);
                shB_hi[nxt][s][e] = hi;
                shB_lo[nxt][s][e] = f2bf(holdB[j] - bf2f(hi));
            }
        }
        __syncthreads();
    }

    // ---- write out last-h for both streams ----
    float* hout = dir ? hout_b : hout_f;
    #pragma unroll
    for (int j = 0; j < 4; ++j) {
        if (ordsA[j] >= 0) hout[(size_t)ordsA[j] * HDIM + e] = holdA[j];
        if (ordsB[j] >= 0) hout[(size_t)ordsB[j] * HDIM + e] = holdB[j];
    }
}

// ---------------------------------------------------------------------------
// Head + mean
// ---------------------------------------------------------------------------
__global__ __launch_bounds__(64) void head_kernel(
    const float* __restrict__ hsf, const float* __restrict__ hsb,
    const float* __restrict__ fc1_w, const float* __restrict__ fc1_b,
    const float* __restrict__ fc2_w, const float* __restrict__ fc2_b,
    float* __restrict__ out)
{
    const int br = blockIdx.x;
    const int j = threadIdx.x;
    __shared__ float rev[HDIM];
    for (int ee = j; ee < HDIM; ee += 64)
        rev[ee] = 0.5f * (hsf[(size_t)br * HDIM + ee] + hsb[(size_t)br * HDIM + ee]);
    __syncthreads();
    float acc = 0.f;
    #pragma unroll
    for (int k = 0; k < HDIM; ++k)
        acc = fmaf(fc1_w[(size_t)j * HDIM + k], rev[k], acc);
    acc += fc1_b[j];
    const float alpha = 1.6732632423543772f;
    const float scale = 1.0507009873554805f;
    float h1 = scale * (acc > 0.f ? acc : alpha * (expf(acc) - 1.f));
    float contrib = h1 * fc2_w[j];
    #pragma unroll
    for (int off = 32; off > 0; off >>= 1)
        contrib += __shfl_down(contrib, off);
    if (j == 0) out[16 + br] = contrib + fc2_b[0];
}

__global__ void mean_kernel(float* __restrict__ out)
{
    int b = threadIdx.x;
    if (b < BB) {
        float s = 0.f;
        for (int r = 0; r < RR; ++r) s += out[16 + b * RR + r];
        out[b] = s / (float)RR;
    }
}

// ---------------------------------------------------------------------------
// Launch
// ---------------------------------------------------------------------------
extern "C" void kernel_launch(void* const* d_in, const int* in_sizes, int n_in,
                              void* d_out, int out_size, void* d_ws, size_t ws_size,
                              hipStream_t stream)
{
    const int*   inputs       = (const int*)d_in[0];
    const int*   sent_lengths = (const int*)d_in[1];
    const int*   sent_counts  = (const int*)d_in[2];
    const float* embed   = (const float*)d_in[3];
    const float* wWih_f  = (const float*)d_in[4];
    const float* wWhh_f  = (const float*)d_in[5];
    const float* wbih_f  = (const float*)d_in[6];
    const float* wbhh_f  = (const float*)d_in[7];
    const float* wWih_b  = (const float*)d_in[8];
    const float* wWhh_b  = (const float*)d_in[9];
    const float* wbih_b  = (const float*)d_in[10];
    const float* wbhh_b  = (const float*)d_in[11];
    const float* sWih_f  = (const float*)d_in[12];
    const float* sWhh_f  = (const float*)d_in[13];
    const float* sbih_f  = (const float*)d_in[14];
    const float* sbhh_f  = (const float*)d_in[15];
    const float* sWih_b  = (const float*)d_in[16];
    const float* sWhh_b  = (const float*)d_in[17];
    const float* sbih_b  = (const float*)d_in[18];
    const float* sbhh_b  = (const float*)d_in[19];
    const float* fc1_w   = (const float*)d_in[20];
    const float* fc1_b   = (const float*)d_in[21];
    const float* fc2_w   = (const float*)d_in[22];
    const float* fc2_b   = (const float*)d_in[23];

    float* ws = (float*)d_ws;
    const size_t projT_elems = (size_t)VOCAB * NPROJ;      // 38,400,000
    const size_t xgs_elems   = (size_t)NSENT * NPROJ;      //  2,457,600
    const size_t h_elems     = (size_t)NSENT * HDIM;       //    409,600
    const size_t hs_elems    = (size_t)NREV * HDIM;        //     20,480
    float* projT = ws;
    float* xgs   = projT + projT_elems;
    float* hf    = xgs + xgs_elems;
    float* hb    = hf + h_elems;
    float* hsf   = hb + h_elems;
    float* hsb   = hsf + hs_elems;
    int* order1  = (int*)(hsb + hs_elems);         // [NSENT]
    int* order2  = order1 + NSENT;                 // [NREV]
    short* Bw_hi = (short*)(order2 + NREV);        // [768*224]
    short* Bw_lo = Bw_hi + 768 * 224;
    short* Sw_hi = Bw_lo + 768 * 224;              // [768*128]
    short* Sw_lo = Sw_hi + 768 * 128;

    size_t need = (projT_elems + xgs_elems + 2*h_elems + 2*hs_elems) * sizeof(float)
                + (NSENT + NREV) * sizeof(int)
                + (size_t)(2 * 768 * 224 + 2 * 768 * 128) * sizeof(short);
    if (ws_size < need) return;

    // 0) counting sort + weight-blob preconversion (all tiny)
    sort_all<<<1, 256, 0, stream>>>(sent_lengths, order1, sent_counts, order2);
    {
        int ng = 384 * 224 / 8;
        preconv<EDIM, 224><<<(ng + 255) / 256, 256, 0, stream>>>(
            wWih_f, 384, Bw_hi, Bw_lo, ng);
        preconv<EDIM, 224><<<(ng + 255) / 256, 256, 0, stream>>>(
            wWih_b, 384, Bw_hi + 384 * 224, Bw_lo + 384 * 224, ng);
    }
    {
        int ng = 384 * 128 / 8;
        preconv<HDIM, HDIM><<<(ng + 255) / 256, 256, 0, stream>>>(
            sWih_f, 384, Sw_hi, Sw_lo, ng);
        preconv<HDIM, HDIM><<<(ng + 255) / 256, 256, 0, stream>>>(
            sWih_b, 384, Sw_hi + 384 * 128, Sw_lo + 384 * 128, ng);
    }

    // 1) projected-embedding table (A converted in-kernel, B from blob)
    {
        dim3 grid(NPROJ / 128, (VOCAB + 127) / 128);    // 6 x 391
        gemm_v3<EDIM, 224, false><<<grid, 256, 0, stream>>>(
            embed, nullptr, VOCAB, Bw_hi, Bw_lo, wbih_f, wbih_b, projT);
    }
    // 2) word-level BiGRU last-h (dual-stream scan, 256-VGPR budget)
    {
        int numTiles = NSENT / 16;                      // 200 (even)
        gru_dual<true, WW><<<numTiles, 512, 0, stream>>>(
            projT, inputs, sent_lengths, order1,
            wWhh_f, wWhh_b, wbhh_f, wbhh_b,
            hf, hb, NSENT, numTiles);
    }
    // 3) sentence-level input projections
    {
        dim3 grid(NPROJ / 128, (NSENT + 127) / 128);    // 6 x 25
        gemm_v3<HDIM, HDIM, true><<<grid, 256, 0, stream>>>(
            hf, hb, NSENT, Sw_hi, Sw_lo, sbih_f, sbih_b, xgs);
    }
    // 4) sentence-level BiGRU last-h (dual-stream scan)
    {
        int numTiles = NREV / 16;                       // 10 (even)
        gru_dual<false, SS><<<numTiles, 512, 0, stream>>>(
            xgs, nullptr, sent_counts, order2,
            sWhh_f, sWhh_b, sbhh_f, sbhh_b,
            hsf, hsb, NREV, numTiles);
    }
    // 5) FC head -> r_stars, then p_stars
    head_kernel<<<NREV, 64, 0, stream>>>(hsf, hsb, fc1_w, fc1_b, fc2_w, fc2_b,
                                         (float*)d_out);
    mean_kernel<<<1, 64, 0, stream>>>((float*)d_out);
}